// Round 1
// baseline (1881.752 us; speedup 1.0000x reference)
//
#include <hip/hip_runtime.h>
#include <math.h>

// Problem constants
static constexpr int B  = 2;
static constexpr int S  = 512;
static constexpr int D  = 256;
static constexpr int N  = 16;
static constexpr int DI = 512;
static constexpr int CHUNK = 32;
static constexpr int NCHUNK = S / CHUNK;   // 16
static constexpr int DN = DI * N;          // 8192
static constexpr int KS = 4;               // split-K factor for gpast

// ---------------- LayerNorm: one wave per row (D=256 -> 4 floats/lane) ----------------
__global__ void ln_k(const float* __restrict__ x, const float* __restrict__ w,
                     const float* __restrict__ bias, float* __restrict__ xn) {
    int row = blockIdx.x;           // 0..B*S-1
    int lane = threadIdx.x;         // 0..63
    float4 v = *(const float4*)(x + row * D + lane * 4);
    float s = v.x + v.y + v.z + v.w;
    float q = v.x * v.x + v.y * v.y + v.z * v.z + v.w * v.w;
    for (int m = 1; m < 64; m <<= 1) { s += __shfl_xor(s, m); q += __shfl_xor(q, m); }
    float mu  = s * (1.0f / D);
    float var = q * (1.0f / D) - mu * mu;
    float rs  = rsqrtf(var + 1e-5f);
    float4 wv = *(const float4*)(w + lane * 4);
    float4 bv = *(const float4*)(bias + lane * 4);
    float4 o;
    o.x = (v.x - mu) * rs * wv.x + bv.x;
    o.y = (v.y - mu) * rs * wv.y + bv.y;
    o.z = (v.z - mu) * rs * wv.z + bv.z;
    o.w = (v.w - mu) * rs * wv.w + bv.w;
    *(float4*)(xn + row * D + lane * 4) = o;
}

// ---------------- Generic f32 GEMM: C[M,Nc] = A[M,K] @ W[Nc,K]^T (+res) ----------------
// M,Nc multiples of 64; K multiple of 16. Block 256 threads, 64x64 tile, 4x4 per thread.
__global__ __launch_bounds__(256) void gemm_k(const float* __restrict__ A,
                                              const float* __restrict__ W,
                                              const float* __restrict__ res,
                                              float* __restrict__ C,
                                              int M, int Nc, int K) {
    __shared__ float As[64][17];
    __shared__ float Ws[64][17];
    int tid = threadIdx.x;
    int tx = tid & 15, ty = tid >> 4;
    int row0 = blockIdx.y * 64, col0 = blockIdx.x * 64;
    float acc[4][4] = {};
    int r  = tid >> 2;          // 0..63
    int kb = (tid & 3) * 4;     // 0,4,8,12
    for (int k0 = 0; k0 < K; k0 += 16) {
        float4 va = *(const float4*)(A + (size_t)(row0 + r) * K + k0 + kb);
        float4 vw = *(const float4*)(W + (size_t)(col0 + r) * K + k0 + kb);
        As[r][kb + 0] = va.x; As[r][kb + 1] = va.y; As[r][kb + 2] = va.z; As[r][kb + 3] = va.w;
        Ws[r][kb + 0] = vw.x; Ws[r][kb + 1] = vw.y; Ws[r][kb + 2] = vw.z; Ws[r][kb + 3] = vw.w;
        __syncthreads();
        #pragma unroll
        for (int kk = 0; kk < 16; ++kk) {
            float a[4], bb[4];
            #pragma unroll
            for (int i = 0; i < 4; ++i) a[i] = As[ty * 4 + i][kk];
            #pragma unroll
            for (int j = 0; j < 4; ++j) bb[j] = Ws[tx * 4 + j][kk];
            #pragma unroll
            for (int i = 0; i < 4; ++i)
                #pragma unroll
                for (int j = 0; j < 4; ++j) acc[i][j] += a[i] * bb[j];
        }
        __syncthreads();
    }
    #pragma unroll
    for (int i = 0; i < 4; ++i)
        #pragma unroll
        for (int j = 0; j < 4; ++j) {
            int rr = row0 + ty * 4 + i, cc = col0 + tx * 4 + j;
            float v = acc[i][j];
            if (res) v += res[(size_t)rr * Nc + cc];
            C[(size_t)rr * Nc + cc] = v;
        }
}

// ---------------- Causal conv (full channel mix, DC=4) + bias + silu ----------------
// x_act[b,t,o] = silu(conv_b[o] + sum_k sum_i conv_w[o,i,k] * xp[b,t-3+k,i])
// xp[b,t,i] = xz[b,t,i] (first DI cols of xz). Block: 32 t x 64 o, 256 threads.
__global__ __launch_bounds__(256) void conv_k(const float* __restrict__ xz,
                                              const float* __restrict__ conv_w,
                                              const float* __restrict__ conv_b,
                                              float* __restrict__ x_act) {
    __shared__ float xpL[35][33];
    int tid = threadIdx.x;
    int tx = tid & 15, ty = tid >> 4;
    int o0 = blockIdx.x * 64, t0 = blockIdx.y * 32, b = blockIdx.z;
    float acc[2][4] = {};
    for (int i0 = 0; i0 < DI; i0 += 32) {
        for (int idx = tid; idx < 35 * 32; idx += 256) {
            int rr = idx >> 5, i = idx & 31;
            int t = t0 - 3 + rr;
            xpL[rr][i] = (t >= 0) ? xz[((size_t)(b * S + t)) * (2 * DI) + i0 + i] : 0.0f;
        }
        __syncthreads();
        #pragma unroll 4
        for (int i = 0; i < 32; ++i) {
            float xr[5];
            #pragma unroll
            for (int rr = 0; rr < 5; ++rr) xr[rr] = xpL[2 * ty + rr][i];
            #pragma unroll
            for (int q = 0; q < 4; ++q) {
                int o = o0 + tx * 4 + q;
                float4 w4 = *(const float4*)(conv_w + ((size_t)o * DI + i0 + i) * 4);
                acc[0][q] += xr[0] * w4.x + xr[1] * w4.y + xr[2] * w4.z + xr[3] * w4.w;
                acc[1][q] += xr[1] * w4.x + xr[2] * w4.y + xr[3] * w4.z + xr[4] * w4.w;
            }
        }
        __syncthreads();
    }
    #pragma unroll
    for (int lt = 0; lt < 2; ++lt)
        #pragma unroll
        for (int q = 0; q < 4; ++q) {
            int t = t0 + ty * 2 + lt, o = o0 + tx * 4 + q;
            float v = acc[lt][q] + conv_b[o];
            x_act[((size_t)(b * S + t)) * DI + o] = v / (1.0f + expf(-v));
        }
}

// ---------------- ssm = x_act @ W_xp^T (33 outputs) -> dt_raw, Bm, Cm ----------------
// one wave per row; block 256 = 4 waves.
__global__ void ssm_k(const float* __restrict__ x_act, const float* __restrict__ W_xp,
                      float* __restrict__ dt_raw, float* __restrict__ Bm, float* __restrict__ Cm) {
    int row = blockIdx.x * 4 + (threadIdx.x >> 6);
    int lane = threadIdx.x & 63;
    const float* xr = x_act + (size_t)row * DI + lane * 8;
    float4 v0 = *(const float4*)xr;
    float4 v1 = *(const float4*)(xr + 4);
    for (int j = 0; j < 2 * N + 1; ++j) {
        const float* wr = W_xp + (size_t)j * DI + lane * 8;
        float4 w0 = *(const float4*)wr;
        float4 w1 = *(const float4*)(wr + 4);
        float acc = v0.x * w0.x + v0.y * w0.y + v0.z * w0.z + v0.w * w0.w
                  + v1.x * w1.x + v1.y * w1.y + v1.z * w1.z + v1.w * w1.w;
        for (int m = 1; m < 64; m <<= 1) acc += __shfl_xor(acc, m);
        if (lane == 0) {
            if (j == 0)           dt_raw[row] = acc;
            else if (j < 1 + N)   Bm[(size_t)row * N + (j - 1)] = acc;
            else                  Cm[(size_t)row * N + (j - 1 - N)] = acc;
        }
    }
}

// ---------------- deg[b,t] = max(sum_{s<t} adj[b,t,s],1); flag[t] = t>0 && any_{b,s<t} adj>0 ----
__global__ void deg_k(const float* __restrict__ adj, float* __restrict__ deg, int* __restrict__ flagI) {
    int t = blockIdx.x & (S - 1), b = blockIdx.x >> 9;
    int lane = threadIdx.x;
    const float* row = adj + ((size_t)(b * S + t)) * S;
    float s = 0.0f; bool anyp = false;
    for (int i = lane; i < t; i += 64) { float v = row[i]; s += v; anyp |= (v > 0.0f); }
    for (int m = 1; m < 64; m <<= 1) s += __shfl_xor(s, m);
    bool any = __any(anyp);
    if (lane == 0) {
        deg[b * S + t] = fmaxf(s, 1.0f);
        if (t > 0 && any) atomicOr(flagI + t, 1);
    }
}

// ---------------- Gpast: Gpart[ks][j][b][dn] = sum_{s in ks-range} adj[b,cb+j,s]*hist[s,b,dn] ----
__global__ __launch_bounds__(256) void gpast_k(const float* __restrict__ adj,
                                               const float* __restrict__ hist,
                                               float* __restrict__ Gpart, int c) {
    int tile = blockIdx.x, b = blockIdx.y, ks = blockIdx.z;
    int dn = tile * 256 + threadIdx.x;
    int cb = c * CHUNK;
    int len = cb / KS;                 // 8c
    int s0 = ks * len, s1 = (ks == KS - 1) ? cb : (s0 + len);
    float acc[CHUNK];
    #pragma unroll
    for (int j = 0; j < CHUNK; ++j) acc[j] = 0.0f;
    const float* adjb = adj + ((size_t)(b * S + cb)) * S;  // adjb[j*S + s]
    for (int s = s0; s < s1; ++s) {
        float hv = hist[((size_t)s * B + b) * DN + dn];
        #pragma unroll
        for (int j = 0; j < CHUNK; ++j) acc[j] += adjb[(size_t)j * S + s] * hv;
    }
    #pragma unroll
    for (int j = 0; j < CHUNK; ++j)
        Gpart[((size_t)(ks * CHUNK + j) * B + b) * DN + dn] = acc[j];
}

// ---------------- Scan over one chunk of 32 steps ----------------
// 16 threads per (b,d) lane (one per n). Cross-n mixing (Wr) via 16-lane shuffles.
// Thread-local history of this chunk kept in LDS (dynamic index).
__global__ __launch_bounds__(256) void scan_k(const float* __restrict__ adj,
                                              const float* __restrict__ x_act,
                                              const float* __restrict__ xz,
                                              const float* __restrict__ dt_raw,
                                              const float* __restrict__ Bm,
                                              const float* __restrict__ Cm,
                                              const float* __restrict__ deg,
                                              const int* __restrict__ flagI,
                                              const float* __restrict__ W_dt,
                                              const float* __restrict__ b_dt,
                                              const float* __restrict__ Wr,
                                              const float* __restrict__ br,
                                              const float* __restrict__ Gpart,
                                              float* __restrict__ hist,
                                              float* __restrict__ yz, int c) {
    __shared__ float histL[CHUNK][16][16];   // [step][grp][n]
    int tid = threadIdx.x;
    int n = tid & 15;
    int grp = tid >> 4;
    int gid = blockIdx.x * 16 + grp;         // 0..1023 = (b,d)
    int b = gid >> 9;
    int d = gid & (DI - 1);
    int dn = d * N + n;
    int cb = c * CHUNK;

    float h = (c == 0) ? 0.0f : hist[((size_t)(cb - 1) * B + b) * DN + dn];
    float wr[16];
    #pragma unroll
    for (int m = 0; m < 16; ++m) wr[m] = Wr[n * 16 + m];
    float brn = br[n];
    float wdt = W_dt[d];
    float bdt = b_dt[d];

    for (int j = 0; j < CHUNK; ++j) {
        int t = cb + j;
        int rowbt = b * S + t;
        float dtr = dt_raw[rowbt];
        float vv = dtr * wdt + bdt;
        float e = 1.0f / (1.0f + expf(vv));        // == exp(-softplus(vv))
        float xa = x_act[(size_t)rowbt * DI + d];
        float Bn = Bm[(size_t)rowbt * N + n];
        float Cn = Cm[(size_t)rowbt * N + n];
        h = h * e + xa * Bn;

        // g = (Gpast + intra-chunk) / deg
        float g = 0.0f;
        if (c > 0) {
            const float* gp = Gpart + ((size_t)j * B + b) * DN + dn;
            g = gp[0] + gp[(size_t)CHUNK * B * DN] + gp[(size_t)2 * CHUNK * B * DN] + gp[(size_t)3 * CHUNK * B * DN];
        }
        float a0 = adj[(size_t)rowbt * S + cb + n];
        float a1 = adj[(size_t)rowbt * S + cb + 16 + n];
        for (int sp = 0; sp < j; ++sp) {
            float w = (sp < 16) ? __shfl(a0, sp, 16) : __shfl(a1, sp - 16, 16);
            g += w * histL[sp][grp][n];
        }
        g /= deg[rowbt];

        // boost = 0.1 * silu(g @ Wr^T + br)
        float acc = brn;
        #pragma unroll
        for (int m = 0; m < 16; ++m) acc += __shfl(g, m, 16) * wr[m];
        float boost = 0.1f * acc / (1.0f + expf(-acc));
        if (flagI[t]) h += boost;

        histL[j][grp][n] = h;
        hist[((size_t)t * B + b) * DN + dn] = h;

        // y = sum_n h*Cn ; then y * silu(z)
        float rsum = h * Cn;
        rsum += __shfl_xor(rsum, 1);
        rsum += __shfl_xor(rsum, 2);
        rsum += __shfl_xor(rsum, 4);
        rsum += __shfl_xor(rsum, 8);
        if (n == 0) {
            float zv = xz[(size_t)rowbt * (2 * DI) + DI + d];
            yz[(size_t)rowbt * DI + d] = rsum * (zv / (1.0f + expf(-zv)));
        }
    }
}

// ---------------- launch ----------------
extern "C" void kernel_launch(void* const* d_in, const int* in_sizes, int n_in,
                              void* d_out, int out_size, void* d_ws, size_t ws_size,
                              hipStream_t stream) {
    const float* x      = (const float*)d_in[0];
    const float* adj    = (const float*)d_in[1];
    const float* ln_w   = (const float*)d_in[2];
    const float* ln_b   = (const float*)d_in[3];
    const float* W_in   = (const float*)d_in[4];
    const float* conv_w = (const float*)d_in[5];
    const float* conv_b = (const float*)d_in[6];
    const float* W_xp   = (const float*)d_in[7];
    const float* W_dt   = (const float*)d_in[8];
    const float* b_dt   = (const float*)d_in[9];
    const float* Wr     = (const float*)d_in[10];
    const float* br     = (const float*)d_in[11];
    const float* W_out  = (const float*)d_in[12];
    float* out = (float*)d_out;

    // workspace carve (floats)
    float* ws = (float*)d_ws;
    size_t off = 0;
    float* xn     = ws + off; off += (size_t)B * S * D;          // 262144
    float* xz     = ws + off; off += (size_t)B * S * 2 * DI;     // 1048576
    float* x_act  = ws + off; off += (size_t)B * S * DI;         // 524288
    float* dt_raw = ws + off; off += (size_t)B * S;              // 1024
    float* Bmb    = ws + off; off += (size_t)B * S * N;          // 16384
    float* Cmb    = ws + off; off += (size_t)B * S * N;          // 16384
    float* degp   = ws + off; off += (size_t)B * S;              // 1024
    int*   flagI  = (int*)(ws + off); off += S;                  // 512
    float* hist   = ws + off; off += (size_t)S * B * DN;         // 8388608
    float* Gpart  = ws + off; off += (size_t)KS * CHUNK * B * DN;// 2097152
    float* yz     = ws + off; off += (size_t)B * S * DI;         // 524288

    hipMemsetAsync(flagI, 0, S * sizeof(int), stream);

    ln_k<<<B * S, 64, 0, stream>>>(x, ln_w, ln_b, xn);
    gemm_k<<<dim3(2 * DI / 64, B * S / 64), 256, 0, stream>>>(xn, W_in, nullptr, xz, B * S, 2 * DI, D);
    conv_k<<<dim3(DI / 64, S / 32, B), 256, 0, stream>>>(xz, conv_w, conv_b, x_act);
    ssm_k<<<B * S / 4, 256, 0, stream>>>(x_act, W_xp, dt_raw, Bmb, Cmb);
    deg_k<<<B * S, 64, 0, stream>>>(adj, degp, flagI);

    for (int c = 0; c < NCHUNK; ++c) {
        if (c > 0)
            gpast_k<<<dim3(DN / 256, B, KS), 256, 0, stream>>>(adj, hist, Gpart, c);
        scan_k<<<B * DI / 16, 256, 0, stream>>>(adj, x_act, xz, dt_raw, Bmb, Cmb, degp, flagI,
                                                W_dt, b_dt, Wr, br, Gpart, hist, yz, c);
    }

    gemm_k<<<dim3(D / 64, B * S / 64), 256, 0, stream>>>(yz, W_out, x, out, B * S, D, DI);
}

// Round 2
// 1073.100 us; speedup vs baseline: 1.7536x; 1.7536x over previous
//
#include <hip/hip_runtime.h>
#include <math.h>

// Problem constants
static constexpr int B  = 2;
static constexpr int S  = 512;
static constexpr int D  = 256;
static constexpr int N  = 16;
static constexpr int DI = 512;
static constexpr int CHUNK = 32;
static constexpr int NCHUNK = S / CHUNK;   // 16
static constexpr int DN = DI * N;          // 8192
static constexpr int KS = 8;               // split-s factor for gpast

typedef unsigned int uint32;
typedef unsigned short ushort16;

__device__ __forceinline__ ushort16 f2bf(float f) {
    uint32 u = __float_as_uint(f);
    u = (u + 0x7fffu + ((u >> 16) & 1u)) >> 16;   // RNE
    return (ushort16)u;
}
__device__ __forceinline__ float bf2f(ushort16 u) {
    return __uint_as_float(((uint32)u) << 16);
}

// ---------------- LayerNorm: one wave per row ----------------
__global__ void ln_k(const float* __restrict__ x, const float* __restrict__ w,
                     const float* __restrict__ bias, float* __restrict__ xn) {
    int row = blockIdx.x;
    int lane = threadIdx.x;
    float4 v = *(const float4*)(x + row * D + lane * 4);
    float s = v.x + v.y + v.z + v.w;
    float q = v.x * v.x + v.y * v.y + v.z * v.z + v.w * v.w;
    for (int m = 1; m < 64; m <<= 1) { s += __shfl_xor(s, m); q += __shfl_xor(q, m); }
    float mu  = s * (1.0f / D);
    float var = q * (1.0f / D) - mu * mu;
    float rs  = rsqrtf(var + 1e-5f);
    float4 wv = *(const float4*)(w + lane * 4);
    float4 bv = *(const float4*)(bias + lane * 4);
    float4 o;
    o.x = (v.x - mu) * rs * wv.x + bv.x;
    o.y = (v.y - mu) * rs * wv.y + bv.y;
    o.z = (v.z - mu) * rs * wv.z + bv.z;
    o.w = (v.w - mu) * rs * wv.w + bv.w;
    *(float4*)(xn + row * D + lane * 4) = o;
}

// ---------------- Generic f32 GEMM: C[M,Nc] = A[M,K] @ W[Nc,K]^T (+res) ----------------
__global__ __launch_bounds__(256) void gemm_k(const float* __restrict__ A,
                                              const float* __restrict__ W,
                                              const float* __restrict__ res,
                                              float* __restrict__ C,
                                              int M, int Nc, int K) {
    __shared__ float As[64][17];
    __shared__ float Ws[64][17];
    int tid = threadIdx.x;
    int tx = tid & 15, ty = tid >> 4;
    int row0 = blockIdx.y * 64, col0 = blockIdx.x * 64;
    float acc[4][4] = {};
    int r  = tid >> 2;
    int kb = (tid & 3) * 4;
    for (int k0 = 0; k0 < K; k0 += 16) {
        float4 va = *(const float4*)(A + (size_t)(row0 + r) * K + k0 + kb);
        float4 vw = *(const float4*)(W + (size_t)(col0 + r) * K + k0 + kb);
        As[r][kb + 0] = va.x; As[r][kb + 1] = va.y; As[r][kb + 2] = va.z; As[r][kb + 3] = va.w;
        Ws[r][kb + 0] = vw.x; Ws[r][kb + 1] = vw.y; Ws[r][kb + 2] = vw.z; Ws[r][kb + 3] = vw.w;
        __syncthreads();
        #pragma unroll
        for (int kk = 0; kk < 16; ++kk) {
            float a[4], bb[4];
            #pragma unroll
            for (int i = 0; i < 4; ++i) a[i] = As[ty * 4 + i][kk];
            #pragma unroll
            for (int j = 0; j < 4; ++j) bb[j] = Ws[tx * 4 + j][kk];
            #pragma unroll
            for (int i = 0; i < 4; ++i)
                #pragma unroll
                for (int j = 0; j < 4; ++j) acc[i][j] += a[i] * bb[j];
        }
        __syncthreads();
    }
    #pragma unroll
    for (int i = 0; i < 4; ++i)
        #pragma unroll
        for (int j = 0; j < 4; ++j) {
            int rr = row0 + ty * 4 + i, cc = col0 + tx * 4 + j;
            float v = acc[i][j];
            if (res) v += res[(size_t)rr * Nc + cc];
            C[(size_t)rr * Nc + cc] = v;
        }
}

// ---------------- Causal conv (DC=4) + bias + silu, weights LDS-staged ----------------
__global__ __launch_bounds__(256) void conv_k(const float* __restrict__ xz,
                                              const float* __restrict__ conv_w,
                                              const float* __restrict__ conv_b,
                                              float* __restrict__ x_act) {
    __shared__ float xpL[35][33];
    __shared__ float wS[4 * 32 * 66];   // [k][i][o], o-stride 66
    int tid = threadIdx.x;
    int tx = tid & 15, ty = tid >> 4;
    int o0 = blockIdx.x * 64, t0 = blockIdx.y * 32, b = blockIdx.z;
    float acc[2][4] = {};
    for (int i0 = 0; i0 < DI; i0 += 32) {
        for (int idx = tid; idx < 35 * 32; idx += 256) {
            int rr = idx >> 5, i = idx & 31;
            int t = t0 - 3 + rr;
            xpL[rr][i] = (t >= 0) ? xz[((size_t)(b * S + t)) * (2 * DI) + i0 + i] : 0.0f;
        }
        #pragma unroll
        for (int r = 0; r < 8; ++r) {
            int e = r * 256 + tid;
            int o = e >> 5, i = e & 31;
            float4 w4 = *(const float4*)(conv_w + ((size_t)(o0 + o) * DI + i0 + i) * 4);
            wS[(0 * 32 + i) * 66 + o] = w4.x;
            wS[(1 * 32 + i) * 66 + o] = w4.y;
            wS[(2 * 32 + i) * 66 + o] = w4.z;
            wS[(3 * 32 + i) * 66 + o] = w4.w;
        }
        __syncthreads();
        #pragma unroll 2
        for (int i = 0; i < 32; ++i) {
            float xr[5];
            #pragma unroll
            for (int rr = 0; rr < 5; ++rr) xr[rr] = xpL[2 * ty + rr][i];
            float wv[4][4];
            #pragma unroll
            for (int k = 0; k < 4; ++k) {
                float2 wa = *(const float2*)&wS[(k * 32 + i) * 66 + tx * 4];
                float2 wb = *(const float2*)&wS[(k * 32 + i) * 66 + tx * 4 + 2];
                wv[k][0] = wa.x; wv[k][1] = wa.y; wv[k][2] = wb.x; wv[k][3] = wb.y;
            }
            #pragma unroll
            for (int q = 0; q < 4; ++q)
                #pragma unroll
                for (int k = 0; k < 4; ++k) {
                    acc[0][q] += xr[k]     * wv[k][q];
                    acc[1][q] += xr[k + 1] * wv[k][q];
                }
        }
        __syncthreads();
    }
    #pragma unroll
    for (int lt = 0; lt < 2; ++lt)
        #pragma unroll
        for (int q = 0; q < 4; ++q) {
            int t = t0 + ty * 2 + lt, o = o0 + tx * 4 + q;
            float v = acc[lt][q] + conv_b[o];
            x_act[((size_t)(b * S + t)) * DI + o] = v / (1.0f + expf(-v));
        }
}

// ---------------- ssm = x_act @ W_xp^T (33 outputs) ----------------
__global__ void ssm_k(const float* __restrict__ x_act, const float* __restrict__ W_xp,
                      float* __restrict__ dt_raw, float* __restrict__ Bm, float* __restrict__ Cm) {
    int row = blockIdx.x * 4 + (threadIdx.x >> 6);
    int lane = threadIdx.x & 63;
    const float* xr = x_act + (size_t)row * DI + lane * 8;
    float4 v0 = *(const float4*)xr;
    float4 v1 = *(const float4*)(xr + 4);
    for (int j = 0; j < 2 * N + 1; ++j) {
        const float* wr = W_xp + (size_t)j * DI + lane * 8;
        float4 w0 = *(const float4*)wr;
        float4 w1 = *(const float4*)(wr + 4);
        float acc = v0.x * w0.x + v0.y * w0.y + v0.z * w0.z + v0.w * w0.w
                  + v1.x * w1.x + v1.y * w1.y + v1.z * w1.z + v1.w * w1.w;
        for (int m = 1; m < 64; m <<= 1) acc += __shfl_xor(acc, m);
        if (lane == 0) {
            if (j == 0)           dt_raw[row] = acc;
            else if (j < 1 + N)   Bm[(size_t)row * N + (j - 1)] = acc;
            else                  Cm[(size_t)row * N + (j - 1 - N)] = acc;
        }
    }
}

// ---------------- rdeg = 1/max(sum_{s<t} adj,1); flag[t] ----------------
__global__ void deg_k(const float* __restrict__ adj, float* __restrict__ rdeg, int* __restrict__ flagI) {
    int t = blockIdx.x & (S - 1), b = blockIdx.x >> 9;
    int lane = threadIdx.x;
    const float* row = adj + ((size_t)(b * S + t)) * S;
    float s = 0.0f; bool anyp = false;
    for (int i = lane; i < t; i += 64) { float v = row[i]; s += v; anyp |= (v > 0.0f); }
    for (int m = 1; m < 64; m <<= 1) s += __shfl_xor(s, m);
    bool any = __any(anyp);
    if (lane == 0) {
        rdeg[b * S + t] = 1.0f / fmaxf(s, 1.0f);
        if (t > 0 && any) atomicOr(flagI + t, 1);
    }
}

// ---------------- E = exp(-softplus(dt)), zs = silu(z) ----------------
__global__ void ez_k(const float* __restrict__ dt_raw, const float* __restrict__ W_dt,
                     const float* __restrict__ b_dt, const float* __restrict__ xz,
                     float* __restrict__ E, float* __restrict__ zs) {
    int i = blockIdx.x * 256 + threadIdx.x;     // 0..B*S*DI
    int d = i & (DI - 1);
    int row = i >> 9;
    float vv = dt_raw[row] * W_dt[d] + b_dt[d];
    E[i] = 1.0f / (1.0f + expf(vv));            // == exp(-softplus(vv))
    float z = xz[(size_t)row * (2 * DI) + DI + d];
    zs[i] = z / (1.0f + expf(-z));
}

// ---------------- Gpast: partial sums over past history (bf16 hist) ----------------
__global__ __launch_bounds__(256) void gpast_k(const float* __restrict__ adj,
                                               const ushort16* __restrict__ histb,
                                               float* __restrict__ Gpart, int c) {
    __shared__ float adjT[32][64];     // [j][s-in-range], len<=60
    int tile = blockIdx.x;             // 0..15 (dn tile of 512)
    int b = blockIdx.y, ks = blockIdx.z;
    int tid = threadIdx.x;
    int dn0 = tile * 512 + tid * 2;
    int cb = c * CHUNK;
    int len = cb >> 3;                 // 4c
    int s0 = ks * len;
    // stage adj rows
    {
        int j0 = tid >> 6, lane = tid & 63;
        #pragma unroll
        for (int jj = 0; jj < 8; ++jj) {
            int j = j0 + jj * 4;
            if (lane < len)
                adjT[j][lane] = adj[((size_t)(b * S + cb + j)) * S + s0 + lane];
        }
    }
    __syncthreads();
    float accA[32], accB[32];
    #pragma unroll
    for (int j = 0; j < 32; ++j) { accA[j] = 0.0f; accB[j] = 0.0f; }
    for (int s = 0; s < len; s += 4) {
        float h0[4], h1[4];
        #pragma unroll
        for (int ss = 0; ss < 4; ++ss) {
            uint32 u = *(const uint32*)(histb + ((size_t)(s0 + s + ss) * B + b) * DN + dn0);
            h0[ss] = __uint_as_float(u << 16);
            h1[ss] = __uint_as_float(u & 0xffff0000u);
        }
        #pragma unroll
        for (int j = 0; j < 32; ++j) {
            float4 av = *(const float4*)&adjT[j][s];
            accA[j] += av.x * h0[0]; accB[j] += av.x * h1[0];
            accA[j] += av.y * h0[1]; accB[j] += av.y * h1[1];
            accA[j] += av.z * h0[2]; accB[j] += av.z * h1[2];
            accA[j] += av.w * h0[3]; accB[j] += av.w * h1[3];
        }
    }
    #pragma unroll
    for (int j = 0; j < 32; ++j) {
        float2 o; o.x = accA[j]; o.y = accB[j];
        *(float2*)&Gpart[(((size_t)ks * CHUNK + j) * B + b) * DN + dn0] = o;
    }
}

// ---------------- Scan over one chunk of 32 steps (register history) ----------------
__global__ __launch_bounds__(256) void scan_k(const float* __restrict__ adj,
                                              const float* __restrict__ x_act,
                                              const float* __restrict__ E,
                                              const float* __restrict__ Bm,
                                              const float* __restrict__ Cm,
                                              const float* __restrict__ rdeg,
                                              const int* __restrict__ flagI,
                                              const float* __restrict__ Wr,
                                              const float* __restrict__ br,
                                              const float* __restrict__ Gpart,
                                              ushort16* __restrict__ histb,
                                              float* __restrict__ hlast,
                                              const float* __restrict__ zs,
                                              float* __restrict__ yz, int c) {
    __shared__ float adjblk[CHUNK][CHUNK + 1];
    __shared__ float rdegL[CHUNK];
    __shared__ int   flL[CHUNK];
    int tid = threadIdx.x;
    int n = tid & 15, grp = tid >> 4;
    int gid = blockIdx.x * 16 + grp;        // (b,d): b uniform per block
    int b = gid >> 9, d = gid & (DI - 1);
    int dn = d * N + n;
    int cb = c * CHUNK;
    {
        int j0 = tid >> 5, sp = tid & 31;   // 8 rows x 32 cols per pass
        #pragma unroll
        for (int jj = 0; jj < 4; ++jj)
            adjblk[j0 + jj * 8][sp] = adj[((size_t)(b * S + cb + j0 + jj * 8)) * S + cb + sp];
        if (tid < CHUNK) { rdegL[tid] = rdeg[b * S + cb + tid]; flL[tid] = flagI[cb + tid]; }
    }
    float wr[16];
    #pragma unroll
    for (int m = 0; m < 16; ++m) wr[m] = Wr[n * 16 + m];
    float brn = br[n];
    float h = (c == 0) ? 0.0f : hlast[b * DN + dn];
    __syncthreads();

    float hreg[CHUNK];
    size_t baseTD = ((size_t)(b * S + cb)) * DI + d;   // step stride DI
    size_t baseN  = ((size_t)(b * S + cb)) * N + n;    // step stride N
    size_t baseDN = ((size_t)cb * B + b) * DN + dn;    // step stride B*DN

    #pragma unroll
    for (int j = 0; j < CHUNK; ++j) {
        float e  = E[baseTD + (size_t)j * DI];
        float xa = x_act[baseTD + (size_t)j * DI];
        float Bn = Bm[baseN + (size_t)j * N];
        float Cn = Cm[baseN + (size_t)j * N];
        h = h * e + xa * Bn;

        float g = 0.0f;
        if (c > 0) {
            #pragma unroll
            for (int ks = 0; ks < KS; ++ks)
                g += Gpart[(((size_t)ks * CHUNK + j) * B + b) * DN + dn];
        }
        #pragma unroll
        for (int sp = 0; sp < j; ++sp)
            g += adjblk[j][sp] * hreg[sp];
        g *= rdegL[j];

        float acc0 = brn, acc1 = 0.0f;
        #pragma unroll
        for (int m = 0; m < 16; m += 2) {
            acc0 += __shfl(g, m, 16)     * wr[m];
            acc1 += __shfl(g, m + 1, 16) * wr[m + 1];
        }
        float acc = acc0 + acc1;
        if (flL[j]) h += 0.1f * acc / (1.0f + expf(-acc));

        hreg[j] = h;
        histb[baseDN + (size_t)j * (B * DN)] = f2bf(h);

        float rs = h * Cn;
        rs += __shfl_xor(rs, 1);
        rs += __shfl_xor(rs, 2);
        rs += __shfl_xor(rs, 4);
        rs += __shfl_xor(rs, 8);
        if (n == 0)
            yz[baseTD + (size_t)j * DI] = rs * zs[baseTD + (size_t)j * DI];
    }
    hlast[b * DN + dn] = h;
}

// ---------------- launch ----------------
extern "C" void kernel_launch(void* const* d_in, const int* in_sizes, int n_in,
                              void* d_out, int out_size, void* d_ws, size_t ws_size,
                              hipStream_t stream) {
    const float* x      = (const float*)d_in[0];
    const float* adj    = (const float*)d_in[1];
    const float* ln_w   = (const float*)d_in[2];
    const float* ln_b   = (const float*)d_in[3];
    const float* W_in   = (const float*)d_in[4];
    const float* conv_w = (const float*)d_in[5];
    const float* conv_b = (const float*)d_in[6];
    const float* W_xp   = (const float*)d_in[7];
    const float* W_dt   = (const float*)d_in[8];
    const float* b_dt   = (const float*)d_in[9];
    const float* Wr     = (const float*)d_in[10];
    const float* br     = (const float*)d_in[11];
    const float* W_out  = (const float*)d_in[12];
    float* out = (float*)d_out;

    float* ws = (float*)d_ws;
    size_t off = 0;
    float* xn     = ws + off; off += (size_t)B * S * D;
    float* xz     = ws + off; off += (size_t)B * S * 2 * DI;
    float* x_act  = ws + off; off += (size_t)B * S * DI;
    float* dt_raw = ws + off; off += (size_t)B * S;
    float* Bmb    = ws + off; off += (size_t)B * S * N;
    float* Cmb    = ws + off; off += (size_t)B * S * N;
    float* rdegp  = ws + off; off += (size_t)B * S;
    int*   flagI  = (int*)(ws + off); off += S;
    float* Ebuf   = ws + off; off += (size_t)B * S * DI;
    float* zsbuf  = ws + off; off += (size_t)B * S * DI;
    float* hlast  = ws + off; off += (size_t)B * DN;
    float* Gpart  = ws + off; off += (size_t)KS * CHUNK * B * DN;
    float* yz     = ws + off; off += (size_t)B * S * DI;
    ushort16* histb = (ushort16*)(ws + off); off += (size_t)S * B * DN / 2;

    hipMemsetAsync(flagI, 0, S * sizeof(int), stream);

    ln_k<<<B * S, 64, 0, stream>>>(x, ln_w, ln_b, xn);
    gemm_k<<<dim3(2 * DI / 64, B * S / 64), 256, 0, stream>>>(xn, W_in, nullptr, xz, B * S, 2 * DI, D);
    conv_k<<<dim3(DI / 64, S / 32, B), 256, 0, stream>>>(xz, conv_w, conv_b, x_act);
    ssm_k<<<B * S / 4, 256, 0, stream>>>(x_act, W_xp, dt_raw, Bmb, Cmb);
    deg_k<<<B * S, 64, 0, stream>>>(adj, rdegp, flagI);
    ez_k<<<B * S * DI / 256, 256, 0, stream>>>(dt_raw, W_dt, b_dt, xz, Ebuf, zsbuf);

    for (int c = 0; c < NCHUNK; ++c) {
        if (c > 0)
            gpast_k<<<dim3(DN / 512, B, KS), 256, 0, stream>>>(adj, histb, Gpart, c);
        scan_k<<<B * DI / 16, 256, 0, stream>>>(adj, x_act, Ebuf, Bmb, Cmb, rdegp, flagI,
                                                Wr, br, Gpart, histb, hlast, zsbuf, yz, c);
    }

    gemm_k<<<dim3(D / 64, B * S / 64), 256, 0, stream>>>(yz, W_out, x, out, B * S, D, DI);
}

// Round 3
// 825.952 us; speedup vs baseline: 2.2783x; 1.2992x over previous
//
#include <hip/hip_runtime.h>
#include <math.h>

// Problem constants
static constexpr int B  = 2;
static constexpr int S  = 512;
static constexpr int D  = 256;
static constexpr int N  = 16;
static constexpr int DI = 512;
static constexpr int CHUNK = 32;
static constexpr int NCHUNK = S / CHUNK;   // 16
static constexpr int DN = DI * N;          // 8192
static constexpr int NSLOT = 7;            // 6 old-split slots + 1 new slot

typedef unsigned int uint32;
typedef unsigned short ushort16;
using bf16x8 = __attribute__((ext_vector_type(8))) short;
using f32x4  = __attribute__((ext_vector_type(4))) float;

__device__ __forceinline__ ushort16 f2bf(float f) {
    uint32 u = __float_as_uint(f);
    u = (u + 0x7fffu + ((u >> 16) & 1u)) >> 16;   // RNE
    return (ushort16)u;
}
__device__ __forceinline__ float bf2f(ushort16 u) {
    return __uint_as_float(((uint32)u) << 16);
}

// ---------------- LayerNorm: one wave per row ----------------
__global__ void ln_k(const float* __restrict__ x, const float* __restrict__ w,
                     const float* __restrict__ bias, float* __restrict__ xn) {
    int row = blockIdx.x;
    int lane = threadIdx.x;
    float4 v = *(const float4*)(x + row * D + lane * 4);
    float s = v.x + v.y + v.z + v.w;
    float q = v.x * v.x + v.y * v.y + v.z * v.z + v.w * v.w;
    for (int m = 1; m < 64; m <<= 1) { s += __shfl_xor(s, m); q += __shfl_xor(q, m); }
    float mu  = s * (1.0f / D);
    float var = q * (1.0f / D) - mu * mu;
    float rs  = rsqrtf(var + 1e-5f);
    float4 wv = *(const float4*)(w + lane * 4);
    float4 bv = *(const float4*)(bias + lane * 4);
    float4 o;
    o.x = (v.x - mu) * rs * wv.x + bv.x;
    o.y = (v.y - mu) * rs * wv.y + bv.y;
    o.z = (v.z - mu) * rs * wv.z + bv.z;
    o.w = (v.w - mu) * rs * wv.w + bv.w;
    *(float4*)(xn + row * D + lane * 4) = o;
}

// ---------------- Generic f32 GEMM: C[M,Nc] = A[M,K] @ W[Nc,K]^T (+res) ----------------
__global__ __launch_bounds__(256) void gemm_k(const float* __restrict__ A,
                                              const float* __restrict__ W,
                                              const float* __restrict__ res,
                                              float* __restrict__ C,
                                              int M, int Nc, int K) {
    __shared__ float As[64][17];
    __shared__ float Ws[64][17];
    int tid = threadIdx.x;
    int tx = tid & 15, ty = tid >> 4;
    int row0 = blockIdx.y * 64, col0 = blockIdx.x * 64;
    float acc[4][4] = {};
    int r  = tid >> 2;
    int kb = (tid & 3) * 4;
    for (int k0 = 0; k0 < K; k0 += 16) {
        float4 va = *(const float4*)(A + (size_t)(row0 + r) * K + k0 + kb);
        float4 vw = *(const float4*)(W + (size_t)(col0 + r) * K + k0 + kb);
        As[r][kb + 0] = va.x; As[r][kb + 1] = va.y; As[r][kb + 2] = va.z; As[r][kb + 3] = va.w;
        Ws[r][kb + 0] = vw.x; Ws[r][kb + 1] = vw.y; Ws[r][kb + 2] = vw.z; Ws[r][kb + 3] = vw.w;
        __syncthreads();
        #pragma unroll
        for (int kk = 0; kk < 16; ++kk) {
            float a[4], bb[4];
            #pragma unroll
            for (int i = 0; i < 4; ++i) a[i] = As[ty * 4 + i][kk];
            #pragma unroll
            for (int j = 0; j < 4; ++j) bb[j] = Ws[tx * 4 + j][kk];
            #pragma unroll
            for (int i = 0; i < 4; ++i)
                #pragma unroll
                for (int j = 0; j < 4; ++j) acc[i][j] += a[i] * bb[j];
        }
        __syncthreads();
    }
    #pragma unroll
    for (int i = 0; i < 4; ++i)
        #pragma unroll
        for (int j = 0; j < 4; ++j) {
            int rr = row0 + ty * 4 + i, cc = col0 + tx * 4 + j;
            float v = acc[i][j];
            if (res) v += res[(size_t)rr * Nc + cc];
            C[(size_t)rr * Nc + cc] = v;
        }
}

// ---------------- cast xz[:, :DI] -> xpb (bf16, with 3-row zero halo per batch) ----------------
__global__ void cast_k(const float* __restrict__ xz, ushort16* __restrict__ xpb) {
    int i = blockIdx.x * 256 + threadIdx.x;   // 0..65535, 8 elems each
    int row = i >> 6;                          // 0..1023 (b*S+t)
    int off = (i & 63) * 8;
    int b = row >> 9, t = row & (S - 1);
    float4 v0 = *(const float4*)(xz + (size_t)row * (2 * DI) + off);
    float4 v1 = *(const float4*)(xz + (size_t)row * (2 * DI) + off + 4);
    ushort16 o[8];
    o[0] = f2bf(v0.x); o[1] = f2bf(v0.y); o[2] = f2bf(v0.z); o[3] = f2bf(v0.w);
    o[4] = f2bf(v1.x); o[5] = f2bf(v1.y); o[6] = f2bf(v1.z); o[7] = f2bf(v1.w);
    uint4 pk;
    pk.x = (uint32)o[0] | ((uint32)o[1] << 16);
    pk.y = (uint32)o[2] | ((uint32)o[3] << 16);
    pk.z = (uint32)o[4] | ((uint32)o[5] << 16);
    pk.w = (uint32)o[6] | ((uint32)o[7] << 16);
    *(uint4*)(xpb + ((size_t)(b * (S + 3) + 3 + t)) * DI + off) = pk;
}

// ---------------- Causal conv via bf16 MFMA + bias + silu ----------------
// out tile 32t x 32o per block, 4 waves = 2x2 quadrants of 16x16.
__global__ __launch_bounds__(256) void convm_k(const ushort16* __restrict__ xpb,
                                               const float* __restrict__ conv_w,
                                               const float* __restrict__ conv_b,
                                               float* __restrict__ x_act) {
    __shared__ __align__(16) short AxS[35 * 40];       // [r][i], i-stride 40
    __shared__ __align__(16) short WbS[4 * 32 * 40];   // [k][o][i], i-stride 40
    int tid = threadIdx.x;
    int l = tid & 63, wid = tid >> 6;
    int wm = wid & 1, wn = wid >> 1;
    int o0 = blockIdx.x * 32;
    int mt = blockIdx.y;
    int b = mt >> 4, tl0 = (mt & 15) * 32;
    f32x4 acc = {0.f, 0.f, 0.f, 0.f};

    for (int k0 = 0; k0 < DI; k0 += 32) {
        // stage A rows tl0-3 .. tl0+31 (xpb is +3 haloed)
        if (tid < 140) {
            int r = tid >> 2, seg = tid & 3;
            uint4 v = *(const uint4*)(xpb + ((size_t)(b * (S + 3) + tl0 + r)) * DI + k0 + seg * 8);
            *(uint4*)&AxS[r * 40 + seg * 8] = v;
        }
        // stage W: conv_w[o][i][0..3] float4 -> WbS[k][o][i] bf16
        #pragma unroll
        for (int it = 0; it < 4; ++it) {
            int p = it * 256 + tid;
            int o = p >> 5, i = p & 31;
            float4 w4 = *(const float4*)(conv_w + ((size_t)(o0 + o) * DI + (k0 + i)) * 4);
            WbS[(0 * 32 + o) * 40 + i] = (short)f2bf(w4.x);
            WbS[(1 * 32 + o) * 40 + i] = (short)f2bf(w4.y);
            WbS[(2 * 32 + o) * 40 + i] = (short)f2bf(w4.z);
            WbS[(3 * 32 + o) * 40 + i] = (short)f2bf(w4.w);
        }
        __syncthreads();
        #pragma unroll
        for (int k = 0; k < 4; ++k) {
            bf16x8 aF = *(const bf16x8*)&AxS[(wm * 16 + (l & 15) + k) * 40 + (l >> 4) * 8];
            bf16x8 bF = *(const bf16x8*)&WbS[(k * 32 + wn * 16 + (l & 15)) * 40 + (l >> 4) * 8];
            acc = __builtin_amdgcn_mfma_f32_16x16x32_bf16(aF, bF, acc, 0, 0, 0);
        }
        __syncthreads();
    }
    int oc = o0 + wn * 16 + (l & 15);
    float bia = conv_b[oc];
    #pragma unroll
    for (int reg = 0; reg < 4; ++reg) {
        int m = wm * 16 + (l >> 4) * 4 + reg;
        float v = acc[reg] + bia;
        x_act[((size_t)(b * S + tl0 + m)) * DI + oc] = v / (1.0f + expf(-v));
    }
}

// ---------------- ssm = x_act @ W_xp^T (33 outputs) ----------------
__global__ void ssm_k(const float* __restrict__ x_act, const float* __restrict__ W_xp,
                      float* __restrict__ dt_raw, float* __restrict__ Bm, float* __restrict__ Cm) {
    int row = blockIdx.x * 4 + (threadIdx.x >> 6);
    int lane = threadIdx.x & 63;
    const float* xr = x_act + (size_t)row * DI + lane * 8;
    float4 v0 = *(const float4*)xr;
    float4 v1 = *(const float4*)(xr + 4);
    for (int j = 0; j < 2 * N + 1; ++j) {
        const float* wr = W_xp + (size_t)j * DI + lane * 8;
        float4 w0 = *(const float4*)wr;
        float4 w1 = *(const float4*)(wr + 4);
        float acc = v0.x * w0.x + v0.y * w0.y + v0.z * w0.z + v0.w * w0.w
                  + v1.x * w1.x + v1.y * w1.y + v1.z * w1.z + v1.w * w1.w;
        for (int m = 1; m < 64; m <<= 1) acc += __shfl_xor(acc, m);
        if (lane == 0) {
            if (j == 0)           dt_raw[row] = acc;
            else if (j < 1 + N)   Bm[(size_t)row * N + (j - 1)] = acc;
            else                  Cm[(size_t)row * N + (j - 1 - N)] = acc;
        }
    }
}

// ---------------- rdeg = 1/max(sum_{s<t} adj,1); flag[t] ----------------
__global__ void deg_k(const float* __restrict__ adj, float* __restrict__ rdeg, int* __restrict__ flagI) {
    int t = blockIdx.x & (S - 1), b = blockIdx.x >> 9;
    int lane = threadIdx.x;
    const float* row = adj + ((size_t)(b * S + t)) * S;
    float s = 0.0f; bool anyp = false;
    for (int i = lane; i < t; i += 64) { float v = row[i]; s += v; anyp |= (v > 0.0f); }
    for (int m = 1; m < 64; m <<= 1) s += __shfl_xor(s, m);
    bool any = __any(anyp);
    if (lane == 0) {
        rdeg[b * S + t] = 1.0f / fmaxf(s, 1.0f);
        if (t > 0 && any) atomicOr(flagI + t, 1);
    }
}

// ---------------- E = exp(-softplus(dt)), zs = silu(z) ----------------
__global__ void ez_k(const float* __restrict__ dt_raw, const float* __restrict__ W_dt,
                     const float* __restrict__ b_dt, const float* __restrict__ xz,
                     float* __restrict__ E, float* __restrict__ zs) {
    int i = blockIdx.x * 256 + threadIdx.x;
    int d = i & (DI - 1);
    int row = i >> 9;
    float vv = dt_raw[row] * W_dt[d] + b_dt[d];
    E[i] = 1.0f / (1.0f + expf(vv));
    float z = xz[(size_t)row * (2 * DI) + DI + d];
    zs[i] = z / (1.0f + expf(-z));
}

// ================= fused chunk kernel =================
// blocks [0,64): scan chunk c + emit G_new slice for chunk c+1 (slot 6)
// blocks [64,256): G_old for chunk c+1 over past chunks 0..c-1, compacted into
//                  nv=min(c,6) slots. Gpart is bf16, double-buffered by parity.
__global__ __launch_bounds__(256) void chunk_k(const float* __restrict__ adj,
                                               const float* __restrict__ x_act,
                                               const float* __restrict__ E,
                                               const float* __restrict__ Bm,
                                               const float* __restrict__ Cm,
                                               const float* __restrict__ rdeg,
                                               const int* __restrict__ flagI,
                                               const float* __restrict__ Wr,
                                               const float* __restrict__ br,
                                               ushort16* __restrict__ Gpartb,
                                               ushort16* __restrict__ histb,
                                               float* __restrict__ hlast,
                                               const float* __restrict__ zs,
                                               float* __restrict__ yz, int c) {
    __shared__ float smem[4224];
    int tid = threadIdx.x;
    int cb = c * CHUNK;
    const size_t PSTRIDE = (size_t)CHUNK * B * NSLOT * DN;   // per-parity elems

    if (blockIdx.x < 64) {
        // ---------------- scan role ----------------
        float* adjblk = smem;                 // [32][33]
        float* adjN   = smem + 1056;          // [32][33]
        float* eL     = smem + 2112;          // [32][16]
        float* xaL    = smem + 2624;
        float* BnL    = smem + 3136;
        float* CnL    = smem + 3648;
        float* rdegL  = smem + 4160;          // [32]
        float* flL    = smem + 4192;          // [32]

        int n = tid & 15, grp = tid >> 4;
        int b = blockIdx.x >> 5;
        int d0 = (blockIdx.x & 31) << 4;
        int d = d0 + grp;
        int dn = d * N + n;

        {
            int j8 = tid >> 5, sp = tid & 31;
            #pragma unroll
            for (int jj = 0; jj < 4; ++jj) {
                int j = j8 + jj * 8;
                adjblk[j * 33 + sp] = adj[((size_t)(b * S + cb + j)) * S + cb + sp];
            }
            if (c < NCHUNK - 1) {
                #pragma unroll
                for (int jj = 0; jj < 4; ++jj) {
                    int j = j8 + jj * 8;
                    adjN[j * 33 + sp] = adj[((size_t)(b * S + cb + 32 + j)) * S + cb + sp];
                }
            }
            int js = tid >> 4, dd = tid & 15;
            #pragma unroll
            for (int jj = 0; jj < 2; ++jj) {
                int j = js + jj * 16;
                size_t rb = (size_t)(b * S + cb + j);
                eL [j * 16 + dd] = E    [rb * DI + d0 + dd];
                xaL[j * 16 + dd] = x_act[rb * DI + d0 + dd];
                BnL[j * 16 + dd] = Bm[rb * N + dd];
                CnL[j * 16 + dd] = Cm[rb * N + dd];
            }
            if (tid < 32) {
                rdegL[tid] = rdeg[b * S + cb + tid];
                flL[tid] = (float)flagI[cb + tid];
            }
        }
        float wr[16];
        #pragma unroll
        for (int m = 0; m < 16; ++m) wr[m] = Wr[n * 16 + m];
        float brn = br[n];
        float h = (c == 0) ? 0.0f : hlast[b * DN + dn];
        __syncthreads();

        const ushort16* grd = Gpartb + (size_t)(c & 1) * PSTRIDE;
        float hreg[CHUNK];
        size_t baseTD = ((size_t)(b * S + cb)) * DI + d;
        size_t baseDN = ((size_t)cb * B + b) * DN + dn;

        #pragma unroll
        for (int j = 0; j < CHUNK; ++j) {
            float e  = eL [j * 16 + grp];
            float xa = xaL[j * 16 + grp];
            float Bn = BnL[j * 16 + n];
            float Cn = CnL[j * 16 + n];
            h = h * e + xa * Bn;

            float g = 0.0f;
            const ushort16* gp = grd + ((size_t)(j * B + b) * NSLOT) * DN + dn;
            #pragma unroll
            for (int sl = 0; sl < NSLOT; ++sl) g += bf2f(gp[(size_t)sl * DN]);
            #pragma unroll
            for (int sp = 0; sp < j; ++sp)
                g += adjblk[j * 33 + sp] * hreg[sp];
            g *= rdegL[j];

            float acc0 = brn, acc1 = 0.0f;
            #pragma unroll
            for (int m = 0; m < 16; m += 2) {
                acc0 += __shfl(g, m, 16)     * wr[m];
                acc1 += __shfl(g, m + 1, 16) * wr[m + 1];
            }
            float acc = acc0 + acc1;
            if (flL[j] != 0.0f) h += 0.1f * acc / (1.0f + expf(-acc));

            hreg[j] = h;
            histb[baseDN + (size_t)j * (B * DN)] = f2bf(h);

            float rs = h * Cn;
            rs += __shfl_xor(rs, 1);
            rs += __shfl_xor(rs, 2);
            rs += __shfl_xor(rs, 4);
            rs += __shfl_xor(rs, 8);
            if (n == 0)
                yz[baseTD + (size_t)j * DI] = rs * zs[baseTD + (size_t)j * DI];
        }
        hlast[b * DN + dn] = h;

        // G_new for chunk c+1 (slot 6) from register history
        if (c < NCHUNK - 1) {
            ushort16* gwr = Gpartb + (size_t)((c + 1) & 1) * PSTRIDE;
            #pragma unroll
            for (int jj = 0; jj < CHUNK; ++jj) {
                float gn = 0.0f;
                #pragma unroll
                for (int sp = 0; sp < CHUNK; ++sp)
                    gn += adjN[jj * 33 + sp] * hreg[sp];
                gwr[((size_t)(jj * B + b) * NSLOT + 6) * DN + dn] = f2bf(gn);
            }
        }
    } else {
        // ---------------- gpast role (G_old for chunk c+1) ----------------
        if (c >= NCHUNK - 1 || c == 0) return;
        int idx = blockIdx.x - 64;
        int tile = idx & 15;
        int b = (idx >> 4) & 1;
        int ks = idx >> 5;                    // 0..5
        int nv = (c < 6) ? c : 6;
        if (ks >= nv) return;
        int ch0 = ks * c / nv, ch1 = (ks + 1) * c / nv;
        int s0 = ch0 * CHUNK;
        int len = (ch1 - ch0) * CHUNK;        // <= 96

        float* adjT = smem;                   // [32][100]
        {
            int j0 = tid >> 6, lane = tid & 63;
            #pragma unroll
            for (int jj = 0; jj < 8; ++jj) {
                int j = j0 + jj * 4;
                for (int s = lane; s < len; s += 64)
                    adjT[j * 100 + s] = adj[((size_t)(b * S + cb + CHUNK + j)) * S + s0 + s];
            }
        }
        __syncthreads();

        int dn0 = tile * 512 + tid * 2;
        float accA[CHUNK], accB[CHUNK];
        #pragma unroll
        for (int j = 0; j < CHUNK; ++j) { accA[j] = 0.0f; accB[j] = 0.0f; }
        for (int s = 0; s < len; s += 4) {
            float h0[4], h1[4];
            #pragma unroll
            for (int ss = 0; ss < 4; ++ss) {
                uint32 u = *(const uint32*)(histb + ((size_t)(s0 + s + ss) * B + b) * DN + dn0);
                h0[ss] = __uint_as_float(u << 16);
                h1[ss] = __uint_as_float(u & 0xffff0000u);
            }
            #pragma unroll
            for (int j = 0; j < CHUNK; ++j) {
                float4 av = *(const float4*)&adjT[j * 100 + s];
                accA[j] += av.x * h0[0]; accB[j] += av.x * h1[0];
                accA[j] += av.y * h0[1]; accB[j] += av.y * h1[1];
                accA[j] += av.z * h0[2]; accB[j] += av.z * h1[2];
                accA[j] += av.w * h0[3]; accB[j] += av.w * h1[3];
            }
        }
        ushort16* gwr = Gpartb + (size_t)((c + 1) & 1) * PSTRIDE;
        #pragma unroll
        for (int j = 0; j < CHUNK; ++j) {
            uint32 pk = (uint32)(ushort16)f2bf(accA[j]) | ((uint32)(ushort16)f2bf(accB[j]) << 16);
            *(uint32*)&gwr[((size_t)(j * B + b) * NSLOT + ks) * DN + dn0] = pk;
        }
    }
}

// ---------------- launch ----------------
extern "C" void kernel_launch(void* const* d_in, const int* in_sizes, int n_in,
                              void* d_out, int out_size, void* d_ws, size_t ws_size,
                              hipStream_t stream) {
    const float* x      = (const float*)d_in[0];
    const float* adj    = (const float*)d_in[1];
    const float* ln_w   = (const float*)d_in[2];
    const float* ln_b   = (const float*)d_in[3];
    const float* W_in   = (const float*)d_in[4];
    const float* conv_w = (const float*)d_in[5];
    const float* conv_b = (const float*)d_in[6];
    const float* W_xp   = (const float*)d_in[7];
    const float* W_dt   = (const float*)d_in[8];
    const float* b_dt   = (const float*)d_in[9];
    const float* Wr     = (const float*)d_in[10];
    const float* br     = (const float*)d_in[11];
    const float* W_out  = (const float*)d_in[12];
    float* out = (float*)d_out;

    float* ws = (float*)d_ws;
    size_t off = 0;
    float* xn     = ws + off; off += (size_t)B * S * D;
    float* xz     = ws + off; off += (size_t)B * S * 2 * DI;
    float* x_act  = ws + off; off += (size_t)B * S * DI;
    float* dt_raw = ws + off; off += (size_t)B * S;
    float* Bmb    = ws + off; off += (size_t)B * S * N;
    float* Cmb    = ws + off; off += (size_t)B * S * N;
    float* rdegp  = ws + off; off += (size_t)B * S;
    int*   flagI  = (int*)(ws + off); off += S;
    float* Ebuf   = ws + off; off += (size_t)B * S * DI;
    float* zsbuf  = ws + off; off += (size_t)B * S * DI;
    float* hlast  = ws + off; off += (size_t)B * DN;
    float* yz     = ws + off; off += (size_t)B * S * DI;
    ushort16* histb  = (ushort16*)(ws + off); off += (size_t)S * B * DN / 2;
    ushort16* Gpartb = (ushort16*)(ws + off); off += (size_t)2 * CHUNK * B * NSLOT * DN / 2;
    ushort16* xpb    = (ushort16*)(ws + off); off += (size_t)B * (S + 3) * DI / 2;

    hipMemsetAsync(flagI, 0, S * sizeof(int), stream);
    hipMemsetAsync(Gpartb, 0, (size_t)2 * CHUNK * B * NSLOT * DN * 2, stream);
    hipMemsetAsync(xpb, 0, (size_t)B * (S + 3) * DI * 2, stream);

    ln_k<<<B * S, 64, 0, stream>>>(x, ln_w, ln_b, xn);
    gemm_k<<<dim3(2 * DI / 64, B * S / 64), 256, 0, stream>>>(xn, W_in, nullptr, xz, B * S, 2 * DI, D);
    cast_k<<<B * S * DI / (256 * 8), 256, 0, stream>>>(xz, xpb);
    convm_k<<<dim3(DI / 32, B * S / 32), 256, 0, stream>>>(xpb, conv_w, conv_b, x_act);
    ssm_k<<<B * S / 4, 256, 0, stream>>>(x_act, W_xp, dt_raw, Bmb, Cmb);
    deg_k<<<B * S, 64, 0, stream>>>(adj, rdegp, flagI);
    ez_k<<<B * S * DI / 256, 256, 0, stream>>>(dt_raw, W_dt, b_dt, xz, Ebuf, zsbuf);

    for (int c = 0; c < NCHUNK; ++c)
        chunk_k<<<256, 256, 0, stream>>>(adj, x_act, Ebuf, Bmb, Cmb, rdegp, flagI,
                                         Wr, br, Gpartb, histb, hlast, zsbuf, yz, c);

    gemm_k<<<dim3(D / 64, B * S / 64), 256, 0, stream>>>(yz, W_out, x, out, B * S, D, DI);
}

// Round 4
// 689.734 us; speedup vs baseline: 2.7282x; 1.1975x over previous
//
#include <hip/hip_runtime.h>
#include <math.h>

// Problem constants
static constexpr int B  = 2;
static constexpr int S  = 512;
static constexpr int D  = 256;
static constexpr int N  = 16;
static constexpr int DI = 512;
static constexpr int CHUNK = 32;
static constexpr int NCHUNK = S / CHUNK;   // 16
static constexpr int DN = DI * N;          // 8192
static constexpr int NSLOT = 7;            // 6 old-split slots + 1 new slot

typedef unsigned int uint32;
typedef unsigned short ushort16;
using bf16x8 = __attribute__((ext_vector_type(8))) short;
using f32x4  = __attribute__((ext_vector_type(4))) float;

__device__ __forceinline__ ushort16 f2bf(float f) {
    uint32 u = __float_as_uint(f);
    u = (u + 0x7fffu + ((u >> 16) & 1u)) >> 16;   // RNE
    return (ushort16)u;
}
__device__ __forceinline__ float bf2f(ushort16 u) {
    return __uint_as_float(((uint32)u) << 16);
}
__device__ __forceinline__ float bflo(uint32 u) { return __uint_as_float(u << 16); }
__device__ __forceinline__ float bfhi(uint32 u) { return __uint_as_float(u & 0xffff0000u); }
__device__ __forceinline__ uint32 pk2(float a, float b) {
    return (uint32)(ushort16)f2bf(a) | ((uint32)(ushort16)f2bf(b) << 16);
}

// ---------------- LayerNorm: one wave per row ----------------
__global__ void ln_k(const float* __restrict__ x, const float* __restrict__ w,
                     const float* __restrict__ bias, float* __restrict__ xn) {
    int row = blockIdx.x;
    int lane = threadIdx.x;
    float4 v = *(const float4*)(x + row * D + lane * 4);
    float s = v.x + v.y + v.z + v.w;
    float q = v.x * v.x + v.y * v.y + v.z * v.z + v.w * v.w;
    for (int m = 1; m < 64; m <<= 1) { s += __shfl_xor(s, m); q += __shfl_xor(q, m); }
    float mu  = s * (1.0f / D);
    float var = q * (1.0f / D) - mu * mu;
    float rs  = rsqrtf(var + 1e-5f);
    float4 wv = *(const float4*)(w + lane * 4);
    float4 bv = *(const float4*)(bias + lane * 4);
    float4 o;
    o.x = (v.x - mu) * rs * wv.x + bv.x;
    o.y = (v.y - mu) * rs * wv.y + bv.y;
    o.z = (v.z - mu) * rs * wv.z + bv.z;
    o.w = (v.w - mu) * rs * wv.w + bv.w;
    *(float4*)(xn + row * D + lane * 4) = o;
}

// ---------------- Generic f32 GEMM: C[M,Nc] = A[M,K] @ W[Nc,K]^T (+res) ----------------
__global__ __launch_bounds__(256) void gemm_k(const float* __restrict__ A,
                                              const float* __restrict__ W,
                                              const float* __restrict__ res,
                                              float* __restrict__ C,
                                              int M, int Nc, int K) {
    __shared__ float As[64][17];
    __shared__ float Ws[64][17];
    int tid = threadIdx.x;
    int tx = tid & 15, ty = tid >> 4;
    int row0 = blockIdx.y * 64, col0 = blockIdx.x * 64;
    float acc[4][4] = {};
    int r  = tid >> 2;
    int kb = (tid & 3) * 4;
    for (int k0 = 0; k0 < K; k0 += 16) {
        float4 va = *(const float4*)(A + (size_t)(row0 + r) * K + k0 + kb);
        float4 vw = *(const float4*)(W + (size_t)(col0 + r) * K + k0 + kb);
        As[r][kb + 0] = va.x; As[r][kb + 1] = va.y; As[r][kb + 2] = va.z; As[r][kb + 3] = va.w;
        Ws[r][kb + 0] = vw.x; Ws[r][kb + 1] = vw.y; Ws[r][kb + 2] = vw.z; Ws[r][kb + 3] = vw.w;
        __syncthreads();
        #pragma unroll
        for (int kk = 0; kk < 16; ++kk) {
            float a[4], bb[4];
            #pragma unroll
            for (int i = 0; i < 4; ++i) a[i] = As[ty * 4 + i][kk];
            #pragma unroll
            for (int j = 0; j < 4; ++j) bb[j] = Ws[tx * 4 + j][kk];
            #pragma unroll
            for (int i = 0; i < 4; ++i)
                #pragma unroll
                for (int j = 0; j < 4; ++j) acc[i][j] += a[i] * bb[j];
        }
        __syncthreads();
    }
    #pragma unroll
    for (int i = 0; i < 4; ++i)
        #pragma unroll
        for (int j = 0; j < 4; ++j) {
            int rr = row0 + ty * 4 + i, cc = col0 + tx * 4 + j;
            float v = acc[i][j];
            if (res) v += res[(size_t)rr * Nc + cc];
            C[(size_t)rr * Nc + cc] = v;
        }
}

// ---------------- cast xz[:, :DI] -> xpb (bf16, with 3-row zero halo per batch) ----------------
__global__ void cast_k(const float* __restrict__ xz, ushort16* __restrict__ xpb) {
    int i = blockIdx.x * 256 + threadIdx.x;   // 0..65535, 8 elems each
    int row = i >> 6;                          // 0..1023 (b*S+t)
    int off = (i & 63) * 8;
    int b = row >> 9, t = row & (S - 1);
    float4 v0 = *(const float4*)(xz + (size_t)row * (2 * DI) + off);
    float4 v1 = *(const float4*)(xz + (size_t)row * (2 * DI) + off + 4);
    uint4 pk;
    pk.x = pk2(v0.x, v0.y);
    pk.y = pk2(v0.z, v0.w);
    pk.z = pk2(v1.x, v1.y);
    pk.w = pk2(v1.z, v1.w);
    *(uint4*)(xpb + ((size_t)(b * (S + 3) + 3 + t)) * DI + off) = pk;
}

// ---------------- Causal conv via bf16 MFMA + bias + silu ----------------
__global__ __launch_bounds__(256) void convm_k(const ushort16* __restrict__ xpb,
                                               const float* __restrict__ conv_w,
                                               const float* __restrict__ conv_b,
                                               float* __restrict__ x_act) {
    __shared__ __align__(16) short AxS[35 * 40];       // [r][i], i-stride 40
    __shared__ __align__(16) short WbS[4 * 32 * 40];   // [k][o][i], i-stride 40
    int tid = threadIdx.x;
    int l = tid & 63, wid = tid >> 6;
    int wm = wid & 1, wn = wid >> 1;
    int o0 = blockIdx.x * 32;
    int mt = blockIdx.y;
    int b = mt >> 4, tl0 = (mt & 15) * 32;
    f32x4 acc = {0.f, 0.f, 0.f, 0.f};

    for (int k0 = 0; k0 < DI; k0 += 32) {
        if (tid < 140) {
            int r = tid >> 2, seg = tid & 3;
            uint4 v = *(const uint4*)(xpb + ((size_t)(b * (S + 3) + tl0 + r)) * DI + k0 + seg * 8);
            *(uint4*)&AxS[r * 40 + seg * 8] = v;
        }
        #pragma unroll
        for (int it = 0; it < 4; ++it) {
            int p = it * 256 + tid;
            int o = p >> 5, i = p & 31;
            float4 w4 = *(const float4*)(conv_w + ((size_t)(o0 + o) * DI + (k0 + i)) * 4);
            WbS[(0 * 32 + o) * 40 + i] = (short)f2bf(w4.x);
            WbS[(1 * 32 + o) * 40 + i] = (short)f2bf(w4.y);
            WbS[(2 * 32 + o) * 40 + i] = (short)f2bf(w4.z);
            WbS[(3 * 32 + o) * 40 + i] = (short)f2bf(w4.w);
        }
        __syncthreads();
        #pragma unroll
        for (int k = 0; k < 4; ++k) {
            bf16x8 aF = *(const bf16x8*)&AxS[(wm * 16 + (l & 15) + k) * 40 + (l >> 4) * 8];
            bf16x8 bF = *(const bf16x8*)&WbS[(k * 32 + wn * 16 + (l & 15)) * 40 + (l >> 4) * 8];
            acc = __builtin_amdgcn_mfma_f32_16x16x32_bf16(aF, bF, acc, 0, 0, 0);
        }
        __syncthreads();
    }
    int oc = o0 + wn * 16 + (l & 15);
    float bia = conv_b[oc];
    #pragma unroll
    for (int reg = 0; reg < 4; ++reg) {
        int m = wm * 16 + (l >> 4) * 4 + reg;
        float v = acc[reg] + bia;
        x_act[((size_t)(b * S + tl0 + m)) * DI + oc] = v / (1.0f + expf(-v));
    }
}

// ---------------- ssm = x_act @ W_xp^T (33 outputs) ----------------
__global__ void ssm_k(const float* __restrict__ x_act, const float* __restrict__ W_xp,
                      float* __restrict__ dt_raw, float* __restrict__ Bm, float* __restrict__ Cm) {
    int row = blockIdx.x * 4 + (threadIdx.x >> 6);
    int lane = threadIdx.x & 63;
    const float* xr = x_act + (size_t)row * DI + lane * 8;
    float4 v0 = *(const float4*)xr;
    float4 v1 = *(const float4*)(xr + 4);
    for (int j = 0; j < 2 * N + 1; ++j) {
        const float* wr = W_xp + (size_t)j * DI + lane * 8;
        float4 w0 = *(const float4*)wr;
        float4 w1 = *(const float4*)(wr + 4);
        float acc = v0.x * w0.x + v0.y * w0.y + v0.z * w0.z + v0.w * w0.w
                  + v1.x * w1.x + v1.y * w1.y + v1.z * w1.z + v1.w * w1.w;
        for (int m = 1; m < 64; m <<= 1) acc += __shfl_xor(acc, m);
        if (lane == 0) {
            if (j == 0)           dt_raw[row] = acc;
            else if (j < 1 + N)   Bm[(size_t)row * N + (j - 1)] = acc;
            else                  Cm[(size_t)row * N + (j - 1 - N)] = acc;
        }
    }
}

// ---------------- rdeg = 1/max(sum_{s<t} adj,1); flag[t] ----------------
__global__ void deg_k(const float* __restrict__ adj, float* __restrict__ rdeg, int* __restrict__ flagI) {
    int t = blockIdx.x & (S - 1), b = blockIdx.x >> 9;
    int lane = threadIdx.x;
    const float* row = adj + ((size_t)(b * S + t)) * S;
    float s = 0.0f; bool anyp = false;
    for (int i = lane; i < t; i += 64) { float v = row[i]; s += v; anyp |= (v > 0.0f); }
    for (int m = 1; m < 64; m <<= 1) s += __shfl_xor(s, m);
    bool any = __any(anyp);
    if (lane == 0) {
        rdeg[b * S + t] = 1.0f / fmaxf(s, 1.0f);
        if (t > 0 && any) atomicOr(flagI + t, 1);
    }
}

// ---------------- E = exp(-softplus(dt)), zs = silu(z) ----------------
__global__ void ez_k(const float* __restrict__ dt_raw, const float* __restrict__ W_dt,
                     const float* __restrict__ b_dt, const float* __restrict__ xz,
                     float* __restrict__ E, float* __restrict__ zs) {
    int i = blockIdx.x * 256 + threadIdx.x;
    int d = i & (DI - 1);
    int row = i >> 9;
    float vv = dt_raw[row] * W_dt[d] + b_dt[d];
    E[i] = 1.0f / (1.0f + expf(vv));
    float z = xz[(size_t)row * (2 * DI) + DI + d];
    zs[i] = z / (1.0f + expf(-z));
}

// ================= fused chunk kernel =================
// Gpart layout: [parity][slot][b][dn][j]  (bf16, j contiguous -> coalesced 16B ops)
// blocks [0,64): scan chunk c + emit G_new slice for chunk c+1 (slot 6)
// blocks [64,256): G_old for chunk c+1, compacted into nv=min(c,6) slots
__global__ __launch_bounds__(256) void chunk_k(const float* __restrict__ adj,
                                               const float* __restrict__ x_act,
                                               const float* __restrict__ E,
                                               const float* __restrict__ Bm,
                                               const float* __restrict__ Cm,
                                               const float* __restrict__ rdeg,
                                               const int* __restrict__ flagI,
                                               const float* __restrict__ Wr,
                                               const float* __restrict__ br,
                                               ushort16* __restrict__ Gpartb,
                                               ushort16* __restrict__ histb,
                                               float* __restrict__ hlast,
                                               const float* __restrict__ zs,
                                               float* __restrict__ yz, int c) {
    __shared__ float smem[4224];
    int tid = threadIdx.x;
    int cb = c * CHUNK;
    const size_t PSTRIDE = (size_t)NSLOT * B * DN * 32;   // ushorts per parity

    if (blockIdx.x < 64) {
        // ---------------- scan role ----------------
        float* adjblk = smem;                 // [32][33]
        float* adjN   = smem + 1056;          // [32][33]
        float* eL     = smem + 2112;          // [32][16]
        float* xaL    = smem + 2624;
        float* BnL    = smem + 3136;
        float* CnL    = smem + 3648;
        float* rdegL  = smem + 4160;          // [32]
        float* flL    = smem + 4192;          // [32]

        int n = tid & 15, grp = tid >> 4;
        int b = blockIdx.x >> 5;
        int d0 = (blockIdx.x & 31) << 4;
        int d = d0 + grp;
        int dn = d * N + n;

        {
            int j8 = tid >> 5, sp = tid & 31;
            #pragma unroll
            for (int jj = 0; jj < 4; ++jj) {
                int j = j8 + jj * 8;
                adjblk[j * 33 + sp] = adj[((size_t)(b * S + cb + j)) * S + cb + sp];
            }
            if (c < NCHUNK - 1) {
                #pragma unroll
                for (int jj = 0; jj < 4; ++jj) {
                    int j = j8 + jj * 8;
                    adjN[j * 33 + sp] = adj[((size_t)(b * S + cb + 32 + j)) * S + cb + sp];
                }
            }
            int js = tid >> 4, dd = tid & 15;
            #pragma unroll
            for (int jj = 0; jj < 2; ++jj) {
                int j = js + jj * 16;
                size_t rb = (size_t)(b * S + cb + j);
                eL [j * 16 + dd] = E    [rb * DI + d0 + dd];
                xaL[j * 16 + dd] = x_act[rb * DI + d0 + dd];
                BnL[j * 16 + dd] = Bm[rb * N + dd];
                CnL[j * 16 + dd] = Cm[rb * N + dd];
            }
            if (tid < 32) {
                rdegL[tid] = rdeg[b * S + cb + tid];
                flL[tid] = (float)flagI[cb + tid];
            }
        }

        // ---- pre-sum all 7 Gpart slots into registers (one coalesced burst) ----
        float gsum[CHUNK];
        #pragma unroll
        for (int j = 0; j < CHUNK; ++j) gsum[j] = 0.0f;
        {
            const ushort16* gb = Gpartb + (size_t)(c & 1) * PSTRIDE;
            #pragma unroll
            for (int sl = 0; sl < NSLOT; ++sl) {
                const ushort16* p = gb + (((size_t)sl * B + b) * DN + dn) * 32;
                #pragma unroll
                for (int qi = 0; qi < 4; ++qi) {
                    uint4 q = *(const uint4*)(p + qi * 8);
                    gsum[qi * 8 + 0] += bflo(q.x); gsum[qi * 8 + 1] += bfhi(q.x);
                    gsum[qi * 8 + 2] += bflo(q.y); gsum[qi * 8 + 3] += bfhi(q.y);
                    gsum[qi * 8 + 4] += bflo(q.z); gsum[qi * 8 + 5] += bfhi(q.z);
                    gsum[qi * 8 + 6] += bflo(q.w); gsum[qi * 8 + 7] += bfhi(q.w);
                }
            }
        }

        float wr[16];
        #pragma unroll
        for (int m = 0; m < 16; ++m) wr[m] = Wr[n * 16 + m];
        float brn = br[n];
        float h = (c == 0) ? 0.0f : hlast[b * DN + dn];
        __syncthreads();

        float hreg[CHUNK];
        #pragma unroll
        for (int j = 0; j < CHUNK; ++j) {
            float e  = eL [j * 16 + grp];
            float xa = xaL[j * 16 + grp];
            float Bn = BnL[j * 16 + n];
            h = h * e + xa * Bn;

            float gacc[4] = {0.0f, 0.0f, 0.0f, 0.0f};
            #pragma unroll
            for (int sp = 0; sp < j; ++sp)
                gacc[sp & 3] += adjblk[j * 33 + sp] * hreg[sp];
            float g = ((gacc[0] + gacc[1]) + (gacc[2] + gacc[3]) + gsum[j]) * rdegL[j];

            float acc0 = brn, acc1 = 0.0f;
            #pragma unroll
            for (int m = 0; m < 16; m += 2) {
                acc0 += __shfl(g, m, 16)     * wr[m];
                acc1 += __shfl(g, m + 1, 16) * wr[m + 1];
            }
            float acc = acc0 + acc1;
            if (flL[j] != 0.0f) h += 0.1f * acc / (1.0f + expf(-acc));
            hreg[j] = h;
        }
        hlast[b * DN + dn] = h;

        // ---- tail: hist writes, y outputs (off the serial chain) ----
        size_t baseTD = ((size_t)(b * S + cb)) * DI + d;
        size_t baseDN = ((size_t)cb * B + b) * DN + dn;
        #pragma unroll
        for (int j = 0; j < CHUNK; ++j)
            histb[baseDN + (size_t)j * (B * DN)] = f2bf(hreg[j]);
        #pragma unroll
        for (int j = 0; j < CHUNK; ++j) {
            float rs = hreg[j] * CnL[j * 16 + n];
            rs += __shfl_xor(rs, 1);
            rs += __shfl_xor(rs, 2);
            rs += __shfl_xor(rs, 4);
            rs += __shfl_xor(rs, 8);
            if (n == 0)
                yz[baseTD + (size_t)j * DI] = rs * zs[baseTD + (size_t)j * DI];
        }

        // ---- G_new for chunk c+1 (slot 6) from register history ----
        if (c < NCHUNK - 1) {
            float gn[CHUNK];
            #pragma unroll
            for (int jj = 0; jj < CHUNK; ++jj) {
                float a0 = 0.0f, a1 = 0.0f;
                #pragma unroll
                for (int sp = 0; sp < CHUNK; sp += 2) {
                    a0 += adjN[jj * 33 + sp]     * hreg[sp];
                    a1 += adjN[jj * 33 + sp + 1] * hreg[sp + 1];
                }
                gn[jj] = a0 + a1;
            }
            ushort16* gw = Gpartb + (size_t)((c + 1) & 1) * PSTRIDE
                         + (((size_t)6 * B + b) * DN + dn) * 32;
            #pragma unroll
            for (int qi = 0; qi < 4; ++qi) {
                uint4 q;
                q.x = pk2(gn[qi * 8 + 0], gn[qi * 8 + 1]);
                q.y = pk2(gn[qi * 8 + 2], gn[qi * 8 + 3]);
                q.z = pk2(gn[qi * 8 + 4], gn[qi * 8 + 5]);
                q.w = pk2(gn[qi * 8 + 6], gn[qi * 8 + 7]);
                *(uint4*)(gw + qi * 8) = q;
            }
        }
    } else {
        // ---------------- gpast role (G_old for chunk c+1) ----------------
        if (c >= NCHUNK - 1 || c == 0) return;
        int idx = blockIdx.x - 64;
        int tile = idx & 15;
        int b = (idx >> 4) & 1;
        int ks = idx >> 5;                    // 0..5
        int nv = (c < 6) ? c : 6;
        if (ks >= nv) return;
        int ch0 = ks * c / nv, ch1 = (ks + 1) * c / nv;
        int s0 = ch0 * CHUNK;
        int len = (ch1 - ch0) * CHUNK;        // <= 96

        float* adjT = smem;                   // [32][100]
        {
            int j0 = tid >> 6, lane = tid & 63;
            #pragma unroll
            for (int jj = 0; jj < 8; ++jj) {
                int j = j0 + jj * 4;
                for (int s = lane; s < len; s += 64)
                    adjT[j * 100 + s] = adj[((size_t)(b * S + cb + CHUNK + j)) * S + s0 + s];
            }
        }
        __syncthreads();

        int dn0 = tile * 512 + tid * 2;
        float accA[CHUNK], accB[CHUNK];
        #pragma unroll
        for (int j = 0; j < CHUNK; ++j) { accA[j] = 0.0f; accB[j] = 0.0f; }
        for (int s = 0; s < len; s += 4) {
            float h0[4], h1[4];
            #pragma unroll
            for (int ss = 0; ss < 4; ++ss) {
                uint32 u = *(const uint32*)(histb + ((size_t)(s0 + s + ss) * B + b) * DN + dn0);
                h0[ss] = bflo(u);
                h1[ss] = bfhi(u);
            }
            #pragma unroll
            for (int j = 0; j < CHUNK; ++j) {
                float4 av = *(const float4*)&adjT[j * 100 + s];
                accA[j] += av.x * h0[0]; accB[j] += av.x * h1[0];
                accA[j] += av.y * h0[1]; accB[j] += av.y * h1[1];
                accA[j] += av.z * h0[2]; accB[j] += av.z * h1[2];
                accA[j] += av.w * h0[3]; accB[j] += av.w * h1[3];
            }
        }
        ushort16* gw0 = Gpartb + (size_t)((c + 1) & 1) * PSTRIDE
                      + (((size_t)ks * B + b) * DN + dn0) * 32;
        #pragma unroll
        for (int qi = 0; qi < 4; ++qi) {
            uint4 qa, qb;
            qa.x = pk2(accA[qi * 8 + 0], accA[qi * 8 + 1]);
            qa.y = pk2(accA[qi * 8 + 2], accA[qi * 8 + 3]);
            qa.z = pk2(accA[qi * 8 + 4], accA[qi * 8 + 5]);
            qa.w = pk2(accA[qi * 8 + 6], accA[qi * 8 + 7]);
            qb.x = pk2(accB[qi * 8 + 0], accB[qi * 8 + 1]);
            qb.y = pk2(accB[qi * 8 + 2], accB[qi * 8 + 3]);
            qb.z = pk2(accB[qi * 8 + 4], accB[qi * 8 + 5]);
            qb.w = pk2(accB[qi * 8 + 6], accB[qi * 8 + 7]);
            *(uint4*)(gw0 + qi * 8) = qa;
            *(uint4*)(gw0 + 32 + qi * 8) = qb;
        }
    }
}

// ---------------- launch ----------------
extern "C" void kernel_launch(void* const* d_in, const int* in_sizes, int n_in,
                              void* d_out, int out_size, void* d_ws, size_t ws_size,
                              hipStream_t stream) {
    const float* x      = (const float*)d_in[0];
    const float* adj    = (const float*)d_in[1];
    const float* ln_w   = (const float*)d_in[2];
    const float* ln_b   = (const float*)d_in[3];
    const float* W_in   = (const float*)d_in[4];
    const float* conv_w = (const float*)d_in[5];
    const float* conv_b = (const float*)d_in[6];
    const float* W_xp   = (const float*)d_in[7];
    const float* W_dt   = (const float*)d_in[8];
    const float* b_dt   = (const float*)d_in[9];
    const float* Wr     = (const float*)d_in[10];
    const float* br     = (const float*)d_in[11];
    const float* W_out  = (const float*)d_in[12];
    float* out = (float*)d_out;

    float* ws = (float*)d_ws;
    size_t off = 0;
    float* xn     = ws + off; off += (size_t)B * S * D;
    float* xz     = ws + off; off += (size_t)B * S * 2 * DI;
    float* x_act  = ws + off; off += (size_t)B * S * DI;
    float* dt_raw = ws + off; off += (size_t)B * S;
    float* Bmb    = ws + off; off += (size_t)B * S * N;
    float* Cmb    = ws + off; off += (size_t)B * S * N;
    float* rdegp  = ws + off; off += (size_t)B * S;
    int*   flagI  = (int*)(ws + off); off += S;
    float* Ebuf   = ws + off; off += (size_t)B * S * DI;
    float* zsbuf  = ws + off; off += (size_t)B * S * DI;
    float* hlast  = ws + off; off += (size_t)B * DN;
    float* yz     = ws + off; off += (size_t)B * S * DI;
    ushort16* histb  = (ushort16*)(ws + off); off += (size_t)S * B * DN / 2;
    ushort16* Gpartb = (ushort16*)(ws + off); off += (size_t)2 * NSLOT * B * DN * 32 / 2;
    ushort16* xpb    = (ushort16*)(ws + off); off += (size_t)B * (S + 3) * DI / 2;

    hipMemsetAsync(flagI, 0, S * sizeof(int), stream);
    hipMemsetAsync(Gpartb, 0, (size_t)2 * NSLOT * B * DN * 32 * 2, stream);
    hipMemsetAsync(xpb, 0, (size_t)B * (S + 3) * DI * 2, stream);

    ln_k<<<B * S, 64, 0, stream>>>(x, ln_w, ln_b, xn);
    gemm_k<<<dim3(2 * DI / 64, B * S / 64), 256, 0, stream>>>(xn, W_in, nullptr, xz, B * S, 2 * DI, D);
    cast_k<<<B * S * DI / (256 * 8), 256, 0, stream>>>(xz, xpb);
    convm_k<<<dim3(DI / 32, B * S / 32), 256, 0, stream>>>(xpb, conv_w, conv_b, x_act);
    ssm_k<<<B * S / 4, 256, 0, stream>>>(x_act, W_xp, dt_raw, Bmb, Cmb);
    deg_k<<<B * S, 64, 0, stream>>>(adj, rdegp, flagI);
    ez_k<<<B * S * DI / 256, 256, 0, stream>>>(dt_raw, W_dt, b_dt, xz, Ebuf, zsbuf);

    for (int c = 0; c < NCHUNK; ++c)
        chunk_k<<<256, 256, 0, stream>>>(adj, x_act, Ebuf, Bmb, Cmb, rdegp, flagI,
                                         Wr, br, Gpartb, histb, hlast, zsbuf, yz, c);

    gemm_k<<<dim3(D / 64, B * S / 64), 256, 0, stream>>>(yz, W_out, x, out, B * S, D, DI);
}